// Round 6
// baseline (235.181 us; speedup 1.0000x reference)
//
#include <hip/hip_runtime.h>
#include <hip/hip_bf16.h>
#include <math.h>
#include <stdint.h>
#include <string.h>

#define TSEQ 2048
#define DMODEL 1024
#define NH 16
#define HD 64
#define BROWS 4096   // b*t
#define BH 32        // b*h

typedef __attribute__((ext_vector_type(8))) short short8;
typedef __attribute__((ext_vector_type(4))) float floatx4;

#define MFMA16 __builtin_amdgcn_mfma_f32_16x16x32_bf16
// 3-bit chunk-XOR swizzle on 64-short (128 B) rows
#define SWZ8(r, q) ((((q) ^ ((r) & 7)) * 8))

#define QSCALE 0.18033688011112042f   // 0.125 * log2(e); p = exp2(s) = exp(s/log2e)

__device__ __forceinline__ unsigned short bf16_rne(float f) {
    uint32_t u = __float_as_uint(f);
    u += 0x7FFFu + ((u >> 16) & 1u);
    return (unsigned short)(u >> 16);
}

__device__ __forceinline__ uint32_t pack_bf16x2(float a, float b) {
    __hip_bfloat162 h = __float22bfloat162_rn(float2{a, b});  // v_cvt_pk_bf16_f32
    uint32_t r;
    memcpy(&r, &h, 4);
    return r;
}

__device__ __forceinline__ void split_bf16(float f, short& hi, short& lo) {
    uint32_t u = __float_as_uint(f);
    hi = (short)(u >> 16);
    float hif = __uint_as_float(u & 0xFFFF0000u);
    lo = (short)bf16_rne(f - hif);
}

__device__ __forceinline__ void async16(const void* g, void* l) {
    __builtin_amdgcn_global_load_lds(
        (__attribute__((address_space(1))) const uint32_t*)g,
        (__attribute__((address_space(3))) uint32_t*)l, 16, 0, 0);
}

// ---------------------------------------------------------------------------
// Fused pack: y==0 -> x bf16 single; y=1..4 -> W_{q,k,v,o} hi/lo split.
// ---------------------------------------------------------------------------
struct PackArgs {
    const float4* x;
    ushort4* xb;
    const float4* w[4];
    ushort4* wh[4];
    ushort4* wl[4];
};
__global__ __launch_bounds__(256) void pack_all(PackArgs a) {
    const int y = blockIdx.y;
    const int base = blockIdx.x * 256 + threadIdx.x;
    if (y == 0) {
#pragma unroll
        for (int it = 0; it < 4; ++it) {
            int i = base + it * 262144;
            float4 f = a.x[i];
            a.xb[i] = make_ushort4(bf16_rne(f.x), bf16_rne(f.y),
                                   bf16_rne(f.z), bf16_rne(f.w));
        }
    } else {
        int w = y - 1;
        float4 f = a.w[w][base];
        short h0, l0, h1, l1, h2, l2, h3, l3;
        split_bf16(f.x, h0, l0); split_bf16(f.y, h1, l1);
        split_bf16(f.z, h2, l2); split_bf16(f.w, h3, l3);
        a.wh[w][base] = make_ushort4(h0, h1, h2, h3);
        a.wl[w][base] = make_ushort4(l0, l1, l2, l3);
    }
}

// ---------------------------------------------------------------------------
// Fused QKV 2-term GEMM (unchanged from R5): 128x128, BK=64, 768 blocks.
// ---------------------------------------------------------------------------
__global__ __launch_bounds__(256) void gemm_qkv(
    const short* __restrict__ Xb,
    const short* __restrict__ Bqh, const short* __restrict__ Bql,
    const short* __restrict__ Bkh, const short* __restrict__ Bkl,
    const short* __restrict__ Bvh, const short* __restrict__ Bvl,
    short* __restrict__ Qo, short* __restrict__ Ko, short* __restrict__ Vo) {
    __shared__ short sA[128 * 64];
    __shared__ short sBh[128 * 64];
    __shared__ short sBl[128 * 64];
    const int K = DMODEL;

    const int tid = threadIdx.x;
    const int lane = tid & 63, wave = tid >> 6;
    const int quad = lane >> 4, col = lane & 15;
    const int m0 = blockIdx.y * 128, n0 = blockIdx.x * 128;
    const int which = n0 >> 10;
    const int nn0 = n0 & 1023;
    const int wm = wave >> 1, wn = wave & 1;

    const short* Bh = (which == 0) ? Bqh : (which == 1) ? Bkh : Bvh;
    const short* Bl = (which == 0) ? Bql : (which == 1) ? Bkl : Bvl;
    const short* Asrc = Xb + (size_t)m0 * K;
    const short* Bhsrc = Bh + (size_t)nn0 * K;
    const short* Blsrc = Bl + (size_t)nn0 * K;

    const int srow = lane >> 3;
    const int soff = (((lane & 7) ^ srow) * 8);

    floatx4 acc[4][4] = {};

    for (int k0 = 0; k0 < K; k0 += 64) {
        __syncthreads();
#pragma unroll
        for (int j = 0; j < 12; ++j) {
            int idx = wave * 12 + j;
            int buf = idx >> 4;
            int sub = idx & 15;
            const short* s = (buf == 0) ? Asrc : (buf == 1) ? Bhsrc : Blsrc;
            short* d = (buf == 0) ? sA : (buf == 1) ? sBh : sBl;
            async16(s + (size_t)(sub * 8 + srow) * K + k0 + soff, d + sub * 512);
        }
        __syncthreads();

#pragma unroll
        for (int s2 = 0; s2 < 2; ++s2) {
            short8 a_b[4], b_h[4], b_l[4];
#pragma unroll
            for (int mi = 0; mi < 4; ++mi) {
                int r = wm * 64 + mi * 16 + col;
                a_b[mi] = *(const short8*)&sA[r * 64 + SWZ8(r, s2 * 4 + quad)];
            }
#pragma unroll
            for (int ni = 0; ni < 4; ++ni) {
                int r = wn * 64 + ni * 16 + col;
                b_h[ni] = *(const short8*)&sBh[r * 64 + SWZ8(r, s2 * 4 + quad)];
                b_l[ni] = *(const short8*)&sBl[r * 64 + SWZ8(r, s2 * 4 + quad)];
            }
#pragma unroll
            for (int mi = 0; mi < 4; ++mi)
#pragma unroll
                for (int ni = 0; ni < 4; ++ni) {
                    acc[mi][ni] = MFMA16(a_b[mi], b_h[ni], acc[mi][ni], 0, 0, 0);
                    acc[mi][ni] = MFMA16(a_b[mi], b_l[ni], acc[mi][ni], 0, 0, 0);
                }
        }
    }

    const int mb = m0 + wm * 64;
    const int nlb = nn0 + wn * 64;
    if (which == 2) {
#pragma unroll
        for (int ni = 0; ni < 4; ++ni) {
            int n = nlb + ni * 16 + col;
            int h = n >> 6, hd = n & 63;
#pragma unroll
            for (int mi = 0; mi < 4; ++mi) {
                int m4 = mb + mi * 16 + quad * 4;
                int b = m4 >> 11, t0 = m4 & 2047;
                int chunk = (t0 >> 3) & 7;
                int tsw = (t0 & ~63) | (((chunk ^ (hd & 7)) << 3) | (t0 & 7));
                size_t row = ((size_t)(b * NH + h) * HD + hd) * TSEQ;
                *(ushort4*)&Vo[row + tsw] =
                    make_ushort4(bf16_rne(acc[mi][ni][0]), bf16_rne(acc[mi][ni][1]),
                                 bf16_rne(acc[mi][ni][2]), bf16_rne(acc[mi][ni][3]));
            }
        }
    } else {
        short* O = (which == 0) ? Qo : Ko;
        const float sc = (which == 0) ? QSCALE : 1.0f;
#pragma unroll
        for (int ni = 0; ni < 4; ++ni) {
            int n = nlb + ni * 16 + col;
            int h = n >> 6, hd = n & 63;
#pragma unroll
            for (int mi = 0; mi < 4; ++mi)
#pragma unroll
                for (int r = 0; r < 4; ++r) {
                    int m = mb + mi * 16 + quad * 4 + r;
                    int b = m >> 11, t = m & 2047;
                    int hds = (which == 1) ? ((((hd >> 3) ^ (t & 7)) << 3) | (hd & 7)) : hd;
                    O[((size_t)(b * NH + h) * TSEQ + t) * HD + hds] =
                        bf16_rne(acc[mi][ni][r] * sc);
                }
        }
    }
}

// ---------------------------------------------------------------------------
// Flash attention, transposed form (S^T = K Q^T, O^T = V^T P^T), 32 q/wave.
// 256 thr = 4 waves, 128 q/block, 128 keys per barrier round. Grid (16, 32).
// Per-lane l (C col = q); packed b64 P stores into XOR-swizzled sP.
// ---------------------------------------------------------------------------
__global__ __launch_bounds__(256) void attn_bf16(
    const short* __restrict__ Qb, const short* __restrict__ Kb,
    const short* __restrict__ Vb, short* __restrict__ Cb) {
    __shared__ short sK[2][64 * 64];
    __shared__ short sV[2][64 * 64];
    __shared__ short sP[4][32 * 64];

    const int tid = threadIdx.x;
    const int lane = tid & 63, wave = tid >> 6;
    const int quad = lane >> 4, col = lane & 15;
    const int qt = blockIdx.x, bh = blockIdx.y;
    const size_t bhoff = (size_t)bh * TSEQ * HD;

    // Q as B-operand frags (n=col=q, k=quad*8+j), pre-scaled 0.125*log2e
    short8 qf[2][2];
#pragma unroll
    for (int qs = 0; qs < 2; ++qs) {
        const size_t qrow = (size_t)(qt * 128 + wave * 32 + qs * 16 + col) * HD;
#pragma unroll
        for (int c = 0; c < 2; ++c)
            qf[qs][c] = *(const short8*)&Qb[bhoff + qrow + c * 32 + quad * 8];
    }

    const int srow = lane >> 3;
    const int schunk = (lane & 7) * 8;   // K/V globally pre-swizzled
    short* sPw = sP[wave];

    float l_r[2] = {};
    floatx4 O[4][2] = {};   // [hd-tile][q-subtile]

    for (int kt = 0; kt < 16; ++kt) {
        __syncthreads();
#pragma unroll
        for (int j = 0; j < 8; ++j) {
            int n = wave * 8 + j;          // 0..31
            int isv = n >> 4;
            int tile = (n >> 3) & 1;
            int sub = n & 7;
            if (!isv) {
                async16(Kb + bhoff + (size_t)(kt * 128 + tile * 64 + sub * 8 + srow) * HD + schunk,
                        &sK[tile][sub * 512]);
            } else {
                async16(Vb + bhoff + (size_t)(sub * 8 + srow) * TSEQ + kt * 128 + tile * 64 + schunk,
                        &sV[tile][sub * 512]);
            }
        }
        __syncthreads();

#pragma unroll
        for (int u = 0; u < 2; ++u) {
            // S^T[key][q]: A = K (m=key), B = Q (n=q)
            floatx4 s[4][2] = {};
#pragma unroll
            for (int k4 = 0; k4 < 4; ++k4) {
                int r = k4 * 16 + col;   // key row
#pragma unroll
                for (int c = 0; c < 2; ++c) {
                    int ch = (((c * 4 + quad) ^ (r & 7)) << 3);
                    short8 kf = *(const short8*)&sK[u][r * 64 + ch];
#pragma unroll
                    for (int qs = 0; qs < 2; ++qs)
                        s[k4][qs] = MFMA16(kf, qf[qs][c], s[k4][qs], 0, 0, 0);
                }
            }

            // p = 2^s; per-lane l (q=col); packed b64 store of 4 consecutive keys
            const int prow = wave * 0 + col;  // row within q-subtile handled below
#pragma unroll
            for (int qs = 0; qs < 2; ++qs) {
                int row = qs * 16 + col;
#pragma unroll
                for (int k4 = 0; k4 < 4; ++k4) {
                    float p0 = __builtin_amdgcn_exp2f(s[k4][qs][0]);
                    float p1 = __builtin_amdgcn_exp2f(s[k4][qs][1]);
                    float p2 = __builtin_amdgcn_exp2f(s[k4][qs][2]);
                    float p3 = __builtin_amdgcn_exp2f(s[k4][qs][3]);
                    l_r[qs] += (p0 + p1) + (p2 + p3);
                    uint2 pk;
                    pk.x = pack_bf16x2(p0, p1);
                    pk.y = pack_bf16x2(p2, p3);
                    int chunk = (2 * k4 + (quad >> 1)) ^ (row & 7);
                    *(uint2*)&sPw[row * 64 + chunk * 8 + (quad & 1) * 4] = pk;
                }
            }

            // O^T[hd][q]: A = V^T (m=hd), B = P^T (n=q, k=key)
#pragma unroll
            for (int c = 0; c < 2; ++c) {
                short8 pf[2];
#pragma unroll
                for (int qs = 0; qs < 2; ++qs) {
                    int row = qs * 16 + col;
                    int ch = ((c * 4 + quad) ^ (row & 7)) * 8;
                    pf[qs] = *(const short8*)&sPw[row * 64 + ch];
                }
#pragma unroll
                for (int ni = 0; ni < 4; ++ni) {
                    int r = ni * 16 + col;   // hd row
                    int ch = (((c * 4 + quad) ^ (r & 7)) << 3);
                    short8 vf = *(const short8*)&sV[u][r * 64 + ch];
#pragma unroll
                    for (int qs = 0; qs < 2; ++qs)
                        O[ni][qs] = MFMA16(vf, pf[qs], O[ni][qs], 0, 0, 0);
                }
            }
        }
    }

    // reduce l over quad partners (lanes col, col+16, col+32, col+48)
    const int b = bh >> 4, h = bh & 15;
#pragma unroll
    for (int qs = 0; qs < 2; ++qs) {
        float t = l_r[qs];
        t += __shfl_xor(t, 16);
        t += __shfl_xor(t, 32);
        float inv = 1.0f / t;
        int trow = qt * 128 + wave * 32 + qs * 16 + col;
        size_t obase = (size_t)(b * TSEQ + trow) * DMODEL + h * 64;
#pragma unroll
        for (int ni = 0; ni < 4; ++ni) {
            uint2 pk;
            pk.x = pack_bf16x2(O[ni][qs][0] * inv, O[ni][qs][1] * inv);
            pk.y = pack_bf16x2(O[ni][qs][2] * inv, O[ni][qs][3] * inv);
            *(uint2*)&Cb[obase + ni * 16 + quad * 4] = pk;
        }
    }
}

// ---------------------------------------------------------------------------
// Out-proj 2-term (unchanged from R5): 128x64 tile, BK=64, 512 blocks.
// ---------------------------------------------------------------------------
__global__ __launch_bounds__(256) void gemm_out(
    const short* __restrict__ Ab,
    const short* __restrict__ Bh, const short* __restrict__ Bl,
    const float* __restrict__ bias, float* __restrict__ Of) {
    __shared__ short sA[128 * 64];
    __shared__ short sBh[64 * 64];
    __shared__ short sBl[64 * 64];
    const int K = DMODEL, N = DMODEL;

    const int tid = threadIdx.x;
    const int lane = tid & 63, wave = tid >> 6;
    const int quad = lane >> 4, col = lane & 15;
    const int m0 = blockIdx.y * 128, n0 = blockIdx.x * 64;
    const int wm = wave >> 1, wn = wave & 1;

    const short* Asrc = Ab + (size_t)m0 * K;
    const short* Bhsrc = Bh + (size_t)n0 * K;
    const short* Blsrc = Bl + (size_t)n0 * K;
    const int srow = lane >> 3;
    const int soff = (((lane & 7) ^ srow) * 8);

    floatx4 acc[4][2] = {};

    for (int k0 = 0; k0 < K; k0 += 64) {
        __syncthreads();
#pragma unroll
        for (int j = 0; j < 8; ++j) {
            int idx = wave * 8 + j;
            int buf = (idx < 16) ? 0 : (idx < 24) ? 1 : 2;
            int sub = (buf == 0) ? idx : (buf == 1) ? idx - 16 : idx - 24;
            const short* s = (buf == 0) ? Asrc : (buf == 1) ? Bhsrc : Blsrc;
            short* d = (buf == 0) ? sA : (buf == 1) ? sBh : sBl;
            async16(s + (size_t)(sub * 8 + srow) * K + k0 + soff, d + sub * 512);
        }
        __syncthreads();

#pragma unroll
        for (int s2 = 0; s2 < 2; ++s2) {
            short8 a_b[4], b_h[2], b_l[2];
#pragma unroll
            for (int mi = 0; mi < 4; ++mi) {
                int r = wm * 64 + mi * 16 + col;
                a_b[mi] = *(const short8*)&sA[r * 64 + SWZ8(r, s2 * 4 + quad)];
            }
#pragma unroll
            for (int ni = 0; ni < 2; ++ni) {
                int r = wn * 32 + ni * 16 + col;
                b_h[ni] = *(const short8*)&sBh[r * 64 + SWZ8(r, s2 * 4 + quad)];
                b_l[ni] = *(const short8*)&sBl[r * 64 + SWZ8(r, s2 * 4 + quad)];
            }
#pragma unroll
            for (int mi = 0; mi < 4; ++mi)
#pragma unroll
                for (int ni = 0; ni < 2; ++ni) {
                    acc[mi][ni] = MFMA16(a_b[mi], b_h[ni], acc[mi][ni], 0, 0, 0);
                    acc[mi][ni] = MFMA16(a_b[mi], b_l[ni], acc[mi][ni], 0, 0, 0);
                }
        }
    }

    const int mb = m0 + wm * 64, nb = n0 + wn * 32;
#pragma unroll
    for (int ni = 0; ni < 2; ++ni) {
        int n = nb + ni * 16 + col;
        float bv = bias[n];
#pragma unroll
        for (int mi = 0; mi < 4; ++mi)
#pragma unroll
            for (int r = 0; r < 4; ++r) {
                int m = mb + mi * 16 + quad * 4 + r;
                Of[(size_t)m * N + n] = acc[mi][ni][r] + bv;
            }
    }
}

// ---------------------------------------------------------------------------
extern "C" void kernel_launch(void* const* d_in, const int* in_sizes, int n_in,
                              void* d_out, int out_size, void* d_ws, size_t ws_size,
                              hipStream_t stream) {
    const float* x  = (const float*)d_in[0];
    const float* Wq = (const float*)d_in[1];
    const float* Wk = (const float*)d_in[2];
    const float* Wv = (const float*)d_in[3];
    const float* Wo = (const float*)d_in[4];
    const float* bo = (const float*)d_in[5];
    float* out = (float*)d_out;

    const size_t NX = (size_t)BROWS * DMODEL;   // 4M
    const size_t NW = (size_t)DMODEL * DMODEL;  // 1M
    short* p = (short*)d_ws;
    short *xb = p;
    short *wqh = xb + NX;  short *wql = wqh + NW;
    short *wkh = wql + NW; short *wkl = wkh + NW;
    short *wvh = wkl + NW; short *wvl = wvh + NW;
    short *woh = wvl + NW; short *wol = woh + NW;
    short *qb = wol + NW;
    short *kb = qb + NX;
    short *vb = kb + NX;
    short *cb = vb + NX;

    PackArgs pa;
    pa.x = (const float4*)x; pa.xb = (ushort4*)xb;
    pa.w[0] = (const float4*)Wq; pa.wh[0] = (ushort4*)wqh; pa.wl[0] = (ushort4*)wql;
    pa.w[1] = (const float4*)Wk; pa.wh[1] = (ushort4*)wkh; pa.wl[1] = (ushort4*)wkl;
    pa.w[2] = (const float4*)Wv; pa.wh[2] = (ushort4*)wvh; pa.wl[2] = (ushort4*)wvl;
    pa.w[3] = (const float4*)Wo; pa.wh[3] = (ushort4*)woh; pa.wl[3] = (ushort4*)wol;
    pack_all<<<dim3(1024, 5), dim3(256), 0, stream>>>(pa);

    gemm_qkv<<<dim3(3 * DMODEL / 128, BROWS / 128), dim3(256), 0, stream>>>(
        xb, wqh, wql, wkh, wkl, wvh, wvl, qb, kb, vb);

    attn_bf16<<<dim3(TSEQ / 128, BH), dim3(256), 0, stream>>>(qb, kb, vb, cb);

    gemm_out<<<dim3(DMODEL / 64, BROWS / 128), dim3(256), 0, stream>>>(cb, woh, wol, bo, out);
}

// Round 7
// 209.565 us; speedup vs baseline: 1.1222x; 1.1222x over previous
//
#include <hip/hip_runtime.h>
#include <hip/hip_bf16.h>
#include <math.h>
#include <stdint.h>
#include <string.h>

#define TSEQ 2048
#define DMODEL 1024
#define NH 16
#define HD 64
#define BROWS 4096   // b*t
#define BH 32        // b*h

typedef __attribute__((ext_vector_type(8))) short short8;
typedef __attribute__((ext_vector_type(4))) float floatx4;

#define MFMA16 __builtin_amdgcn_mfma_f32_16x16x32_bf16
// 3-bit chunk-XOR swizzle on 64-short (128 B) rows
#define SWZ8(r, q) ((((q) ^ ((r) & 7)) * 8))

#define QSCALE 0.18033688011112042f   // 0.125 * log2(e); p = exp2(s) = exp(s/log2e)

__device__ __forceinline__ unsigned short bf16_rne(float f) {
    uint32_t u = __float_as_uint(f);
    u += 0x7FFFu + ((u >> 16) & 1u);
    return (unsigned short)(u >> 16);
}

__device__ __forceinline__ void split_bf16(float f, short& hi, short& lo) {
    uint32_t u = __float_as_uint(f);
    hi = (short)(u >> 16);
    float hif = __uint_as_float(u & 0xFFFF0000u);
    lo = (short)bf16_rne(f - hif);
}

__device__ __forceinline__ void async16(const void* g, void* l) {
    __builtin_amdgcn_global_load_lds(
        (__attribute__((address_space(1))) const uint32_t*)g,
        (__attribute__((address_space(3))) uint32_t*)l, 16, 0, 0);
}

// ---------------------------------------------------------------------------
// Fused pack: y==0 -> x bf16 single (4 float4/thr); y=1..3 -> W_{q,k,v} bf16
// single; y==4 -> Wo hi/lo split (out-proj path has no softmax damping).
// ---------------------------------------------------------------------------
struct PackArgs {
    const float4* x;
    ushort4* xb;
    const float4* w[3];   // Wq, Wk, Wv
    ushort4* wb[3];
    const float4* wo;
    ushort4* woh;
    ushort4* wol;
};
__global__ __launch_bounds__(256) void pack_all(PackArgs a) {
    const int y = blockIdx.y;
    const int base = blockIdx.x * 256 + threadIdx.x;
    if (y == 0) {
#pragma unroll
        for (int it = 0; it < 4; ++it) {
            int i = base + it * 262144;
            float4 f = a.x[i];
            a.xb[i] = make_ushort4(bf16_rne(f.x), bf16_rne(f.y),
                                   bf16_rne(f.z), bf16_rne(f.w));
        }
    } else if (y <= 3) {
        int w = y - 1;
        float4 f = a.w[w][base];
        a.wb[w][base] = make_ushort4(bf16_rne(f.x), bf16_rne(f.y),
                                     bf16_rne(f.z), bf16_rne(f.w));
    } else {
        float4 f = a.wo[base];
        short h0, l0, h1, l1, h2, l2, h3, l3;
        split_bf16(f.x, h0, l0); split_bf16(f.y, h1, l1);
        split_bf16(f.z, h2, l2); split_bf16(f.w, h3, l3);
        a.woh[base] = make_ushort4(h0, h1, h2, h3);
        a.wol[base] = make_ushort4(l0, l1, l2, l3);
    }
}

// ---------------------------------------------------------------------------
// Fused QKV single-bf16 GEMM: [Q|K|V] = x_b @ W_b^T. 128x128 tile, BK=64,
// 768 blocks. 32 KB LDS. Staging: 32 x 1KB per round, 8 per wave.
// ---------------------------------------------------------------------------
__global__ __launch_bounds__(256) void gemm_qkv(
    const short* __restrict__ Xb,
    const short* __restrict__ Bq, const short* __restrict__ Bk,
    const short* __restrict__ Bv,
    short* __restrict__ Qo, short* __restrict__ Ko, short* __restrict__ Vo) {
    __shared__ short sA[128 * 64];
    __shared__ short sB[128 * 64];
    const int K = DMODEL;

    const int tid = threadIdx.x;
    const int lane = tid & 63, wave = tid >> 6;
    const int quad = lane >> 4, col = lane & 15;
    const int m0 = blockIdx.y * 128, n0 = blockIdx.x * 128;
    const int which = n0 >> 10;
    const int nn0 = n0 & 1023;
    const int wm = wave >> 1, wn = wave & 1;

    const short* B = (which == 0) ? Bq : (which == 1) ? Bk : Bv;
    const short* Asrc = Xb + (size_t)m0 * K;
    const short* Bsrc = B + (size_t)nn0 * K;

    const int srow = lane >> 3;
    const int soff = (((lane & 7) ^ srow) * 8);

    floatx4 acc[4][4] = {};

    for (int k0 = 0; k0 < K; k0 += 64) {
        __syncthreads();
#pragma unroll
        for (int j = 0; j < 8; ++j) {
            int idx = wave * 8 + j;             // 0..31: 0-15 sA, 16-31 sB
            int sub = idx & 15;
            const short* s = (idx < 16) ? Asrc : Bsrc;
            short* d = (idx < 16) ? sA : sB;
            async16(s + (size_t)(sub * 8 + srow) * K + k0 + soff, d + sub * 512);
        }
        __syncthreads();

#pragma unroll
        for (int s2 = 0; s2 < 2; ++s2) {
            short8 a_b[4], b_b[4];
#pragma unroll
            for (int mi = 0; mi < 4; ++mi) {
                int r = wm * 64 + mi * 16 + col;
                a_b[mi] = *(const short8*)&sA[r * 64 + SWZ8(r, s2 * 4 + quad)];
            }
#pragma unroll
            for (int ni = 0; ni < 4; ++ni) {
                int r = wn * 64 + ni * 16 + col;
                b_b[ni] = *(const short8*)&sB[r * 64 + SWZ8(r, s2 * 4 + quad)];
            }
#pragma unroll
            for (int mi = 0; mi < 4; ++mi)
#pragma unroll
                for (int ni = 0; ni < 4; ++ni)
                    acc[mi][ni] = MFMA16(a_b[mi], b_b[ni], acc[mi][ni], 0, 0, 0);
        }
    }

    const int mb = m0 + wm * 64;
    const int nlb = nn0 + wn * 64;
    if (which == 2) {
        // V^T [bh][hd][t], key-chunk swizzle within 64-windows; ushort4 along t
#pragma unroll
        for (int ni = 0; ni < 4; ++ni) {
            int n = nlb + ni * 16 + col;
            int h = n >> 6, hd = n & 63;
#pragma unroll
            for (int mi = 0; mi < 4; ++mi) {
                int m4 = mb + mi * 16 + quad * 4;
                int b = m4 >> 11, t0 = m4 & 2047;
                int chunk = (t0 >> 3) & 7;
                int tsw = (t0 & ~63) | (((chunk ^ (hd & 7)) << 3) | (t0 & 7));
                size_t row = ((size_t)(b * NH + h) * HD + hd) * TSEQ;
                *(ushort4*)&Vo[row + tsw] =
                    make_ushort4(bf16_rne(acc[mi][ni][0]), bf16_rne(acc[mi][ni][1]),
                                 bf16_rne(acc[mi][ni][2]), bf16_rne(acc[mi][ni][3]));
            }
        }
    } else {
        short* O = (which == 0) ? Qo : Ko;
        const float sc = (which == 0) ? QSCALE : 1.0f;
#pragma unroll
        for (int ni = 0; ni < 4; ++ni) {
            int n = nlb + ni * 16 + col;
            int h = n >> 6, hd = n & 63;
#pragma unroll
            for (int mi = 0; mi < 4; ++mi)
#pragma unroll
                for (int r = 0; r < 4; ++r) {
                    int m = mb + mi * 16 + quad * 4 + r;
                    int b = m >> 11, t = m & 2047;
                    int hds = (which == 1) ? ((((hd >> 3) ^ (t & 7)) << 3) | (hd & 7)) : hd;
                    O[((size_t)(b * NH + h) * TSEQ + t) * HD + hds] =
                        bf16_rne(acc[mi][ni][r] * sc);
                }
        }
    }
}

// ---------------------------------------------------------------------------
// Flash attention (R5 form — measured best): bf16 MFMA, exp2-domain
// unnormalized softmax. 512 thr = 8 waves, 128 q/block, 128 keys per round.
// ---------------------------------------------------------------------------
__global__ __launch_bounds__(512) void attn_bf16(
    const short* __restrict__ Qb, const short* __restrict__ Kb,
    const short* __restrict__ Vb, short* __restrict__ Cb) {
    __shared__ short sK[2][64 * 64];
    __shared__ short sV[2][64 * 64];
    __shared__ short sP[8][16 * 72];

    const int tid = threadIdx.x;
    const int lane = tid & 63, wave = tid >> 6;
    const int quad = lane >> 4, col = lane & 15;
    const int qt = blockIdx.x, bh = blockIdx.y;
    const size_t bhoff = (size_t)bh * TSEQ * HD;

    const size_t qrow = (size_t)(qt * 128 + wave * 16 + col) * HD;
    short8 qf[2];
#pragma unroll
    for (int c = 0; c < 2; ++c)
        qf[c] = *(const short8*)&Qb[bhoff + qrow + c * 32 + quad * 8];

    const int srow = lane >> 3;
    const int schunk = (lane & 7) * 8;   // K/V globally pre-swizzled

    float l_r[4] = {};
    floatx4 O[4] = {};

    for (int kt = 0; kt < 16; ++kt) {
        __syncthreads();
#pragma unroll
        for (int j = 0; j < 4; ++j) {
            int n = wave * 4 + j;          // 0..31
            int isv = n >> 4;
            int tile = (n >> 3) & 1;
            int sub = n & 7;
            if (!isv) {
                async16(Kb + bhoff + (size_t)(kt * 128 + tile * 64 + sub * 8 + srow) * HD + schunk,
                        &sK[tile][sub * 512]);
            } else {
                async16(Vb + bhoff + (size_t)(sub * 8 + srow) * TSEQ + kt * 128 + tile * 64 + schunk,
                        &sV[tile][sub * 512]);
            }
        }
        __syncthreads();

#pragma unroll
        for (int u = 0; u < 2; ++u) {
            floatx4 s[4] = {};
#pragma unroll
            for (int ni = 0; ni < 4; ++ni) {
                int r = ni * 16 + col;
#pragma unroll
                for (int c = 0; c < 2; ++c) {
                    int ch = (((c * 4 + quad) ^ (r & 7)) << 3);
                    short8 kf = *(const short8*)&sK[u][r * 64 + ch];
                    s[ni] = MFMA16(qf[c], kf, s[ni], 0, 0, 0);
                }
            }

#pragma unroll
            for (int ni = 0; ni < 4; ++ni)
#pragma unroll
                for (int r = 0; r < 4; ++r) {
                    float p = __builtin_amdgcn_exp2f(s[ni][r]);
                    l_r[r] += p;
                    sP[wave][(quad * 4 + r) * 72 + ni * 16 + col] = (short)bf16_rne(p);
                }

#pragma unroll
            for (int c = 0; c < 2; ++c) {
                short8 pf = *(const short8*)&sP[wave][col * 72 + c * 32 + quad * 8];
#pragma unroll
                for (int ni = 0; ni < 4; ++ni) {
                    int r = ni * 16 + col;
                    int ch = (((c * 4 + quad) ^ (r & 7)) << 3);
                    short8 vf = *(const short8*)&sV[u][r * 64 + ch];
                    O[ni] = MFMA16(pf, vf, O[ni], 0, 0, 0);
                }
            }
        }
    }

#pragma unroll
    for (int r = 0; r < 4; ++r) {
        float t = l_r[r];
#pragma unroll
        for (int d = 1; d < 16; d <<= 1) t += __shfl_xor(t, d);
        l_r[r] = 1.0f / t;
    }
    const int b = bh >> 4, h = bh & 15;
#pragma unroll
    for (int r = 0; r < 4; ++r) {
        int t = qt * 128 + wave * 16 + quad * 4 + r;
#pragma unroll
        for (int ni = 0; ni < 4; ++ni) {
            int d = h * 64 + ni * 16 + col;
            Cb[(size_t)(b * TSEQ + t) * DMODEL + d] = bf16_rne(O[ni][r] * l_r[r]);
        }
    }
}

// ---------------------------------------------------------------------------
// Out-proj 2-term (no softmax damping on this path — keep hi/lo):
// 128x64 tile, BK=64, 512 blocks.
// ---------------------------------------------------------------------------
__global__ __launch_bounds__(256) void gemm_out(
    const short* __restrict__ Ab,
    const short* __restrict__ Bh, const short* __restrict__ Bl,
    const float* __restrict__ bias, float* __restrict__ Of) {
    __shared__ short sA[128 * 64];
    __shared__ short sBh[64 * 64];
    __shared__ short sBl[64 * 64];
    const int K = DMODEL, N = DMODEL;

    const int tid = threadIdx.x;
    const int lane = tid & 63, wave = tid >> 6;
    const int quad = lane >> 4, col = lane & 15;
    const int m0 = blockIdx.y * 128, n0 = blockIdx.x * 64;
    const int wm = wave >> 1, wn = wave & 1;

    const short* Asrc = Ab + (size_t)m0 * K;
    const short* Bhsrc = Bh + (size_t)n0 * K;
    const short* Blsrc = Bl + (size_t)n0 * K;
    const int srow = lane >> 3;
    const int soff = (((lane & 7) ^ srow) * 8);

    floatx4 acc[4][2] = {};

    for (int k0 = 0; k0 < K; k0 += 64) {
        __syncthreads();
#pragma unroll
        for (int j = 0; j < 8; ++j) {
            int idx = wave * 8 + j;
            int buf = (idx < 16) ? 0 : (idx < 24) ? 1 : 2;
            int sub = (buf == 0) ? idx : (buf == 1) ? idx - 16 : idx - 24;
            const short* s = (buf == 0) ? Asrc : (buf == 1) ? Bhsrc : Blsrc;
            short* d = (buf == 0) ? sA : (buf == 1) ? sBh : sBl;
            async16(s + (size_t)(sub * 8 + srow) * K + k0 + soff, d + sub * 512);
        }
        __syncthreads();

#pragma unroll
        for (int s2 = 0; s2 < 2; ++s2) {
            short8 a_b[4], b_h[2], b_l[2];
#pragma unroll
            for (int mi = 0; mi < 4; ++mi) {
                int r = wm * 64 + mi * 16 + col;
                a_b[mi] = *(const short8*)&sA[r * 64 + SWZ8(r, s2 * 4 + quad)];
            }
#pragma unroll
            for (int ni = 0; ni < 2; ++ni) {
                int r = wn * 32 + ni * 16 + col;
                b_h[ni] = *(const short8*)&sBh[r * 64 + SWZ8(r, s2 * 4 + quad)];
                b_l[ni] = *(const short8*)&sBl[r * 64 + SWZ8(r, s2 * 4 + quad)];
            }
#pragma unroll
            for (int mi = 0; mi < 4; ++mi)
#pragma unroll
                for (int ni = 0; ni < 2; ++ni) {
                    acc[mi][ni] = MFMA16(a_b[mi], b_h[ni], acc[mi][ni], 0, 0, 0);
                    acc[mi][ni] = MFMA16(a_b[mi], b_l[ni], acc[mi][ni], 0, 0, 0);
                }
        }
    }

    const int mb = m0 + wm * 64, nb = n0 + wn * 32;
#pragma unroll
    for (int ni = 0; ni < 2; ++ni) {
        int n = nb + ni * 16 + col;
        float bv = bias[n];
#pragma unroll
        for (int mi = 0; mi < 4; ++mi)
#pragma unroll
            for (int r = 0; r < 4; ++r) {
                int m = mb + mi * 16 + quad * 4 + r;
                Of[(size_t)m * N + n] = acc[mi][ni][r] + bv;
            }
    }
}

// ---------------------------------------------------------------------------
extern "C" void kernel_launch(void* const* d_in, const int* in_sizes, int n_in,
                              void* d_out, int out_size, void* d_ws, size_t ws_size,
                              hipStream_t stream) {
    const float* x  = (const float*)d_in[0];
    const float* Wq = (const float*)d_in[1];
    const float* Wk = (const float*)d_in[2];
    const float* Wv = (const float*)d_in[3];
    const float* Wo = (const float*)d_in[4];
    const float* bo = (const float*)d_in[5];
    float* out = (float*)d_out;

    const size_t NX = (size_t)BROWS * DMODEL;   // 4M
    const size_t NW = (size_t)DMODEL * DMODEL;  // 1M
    short* p = (short*)d_ws;
    short *xb = p;
    short *wqb = xb + NX;
    short *wkb = wqb + NW;
    short *wvb = wkb + NW;
    short *woh = wvb + NW; short *wol = woh + NW;
    short *qb = wol + NW;
    short *kb = qb + NX;
    short *vb = kb + NX;
    short *cb = vb + NX;

    PackArgs pa;
    pa.x = (const float4*)x; pa.xb = (ushort4*)xb;
    pa.w[0] = (const float4*)Wq; pa.wb[0] = (ushort4*)wqb;
    pa.w[1] = (const float4*)Wk; pa.wb[1] = (ushort4*)wkb;
    pa.w[2] = (const float4*)Wv; pa.wb[2] = (ushort4*)wvb;
    pa.wo = (const float4*)Wo; pa.woh = (ushort4*)woh; pa.wol = (ushort4*)wol;
    pack_all<<<dim3(1024, 5), dim3(256), 0, stream>>>(pa);

    gemm_qkv<<<dim3(3 * DMODEL / 128, BROWS / 128), dim3(256), 0, stream>>>(
        xb, wqb, wkb, wvb, qb, kb, vb);

    attn_bf16<<<dim3(TSEQ / 128, BH), dim3(512), 0, stream>>>(qb, kb, vb, cb);

    gemm_out<<<dim3(DMODEL / 64, BROWS / 128), dim3(256), 0, stream>>>(cb, woh, wol, bo, out);
}

// Round 8
// 199.577 us; speedup vs baseline: 1.1784x; 1.0500x over previous
//
#include <hip/hip_runtime.h>
#include <hip/hip_bf16.h>
#include <math.h>
#include <stdint.h>
#include <string.h>

#define TSEQ 2048
#define DMODEL 1024
#define NH 16
#define HD 64
#define BROWS 4096   // b*t
#define BH 32        // b*h

typedef __attribute__((ext_vector_type(8))) short short8;
typedef __attribute__((ext_vector_type(4))) float floatx4;

#define MFMA16 __builtin_amdgcn_mfma_f32_16x16x32_bf16
// 3-bit chunk-XOR swizzle on 64-short (128 B) rows
#define SWZ8(r, q) ((((q) ^ ((r) & 7)) * 8))

#define QSCALE 0.18033688011112042f   // 0.125 * log2(e); p = exp2(s) = exp(s/log2e)

__device__ __forceinline__ unsigned short bf16_rne(float f) {
    uint32_t u = __float_as_uint(f);
    u += 0x7FFFu + ((u >> 16) & 1u);
    return (unsigned short)(u >> 16);
}

__device__ __forceinline__ uint32_t pack_bf16x2(float a, float b) {
    __hip_bfloat162 h = __float22bfloat162_rn(float2{a, b});
    uint32_t r;
    memcpy(&r, &h, 4);
    return r;
}

__device__ __forceinline__ void split_bf16(float f, short& hi, short& lo) {
    uint32_t u = __float_as_uint(f);
    hi = (short)(u >> 16);
    float hif = __uint_as_float(u & 0xFFFF0000u);
    lo = (short)bf16_rne(f - hif);
}

__device__ __forceinline__ void async16(const void* g, void* l) {
    __builtin_amdgcn_global_load_lds(
        (__attribute__((address_space(1))) const uint32_t*)g,
        (__attribute__((address_space(3))) uint32_t*)l, 16, 0, 0);
}

// ---------------------------------------------------------------------------
// Fused pack (unchanged from R7)
// ---------------------------------------------------------------------------
struct PackArgs {
    const float4* x;
    ushort4* xb;
    const float4* w[3];   // Wq, Wk, Wv
    ushort4* wb[3];
    const float4* wo;
    ushort4* woh;
    ushort4* wol;
};
__global__ __launch_bounds__(256) void pack_all(PackArgs a) {
    const int y = blockIdx.y;
    const int base = blockIdx.x * 256 + threadIdx.x;
    if (y == 0) {
#pragma unroll
        for (int it = 0; it < 4; ++it) {
            int i = base + it * 262144;
            float4 f = a.x[i];
            a.xb[i] = make_ushort4(bf16_rne(f.x), bf16_rne(f.y),
                                   bf16_rne(f.z), bf16_rne(f.w));
        }
    } else if (y <= 3) {
        int w = y - 1;
        float4 f = a.w[w][base];
        a.wb[w][base] = make_ushort4(bf16_rne(f.x), bf16_rne(f.y),
                                     bf16_rne(f.z), bf16_rne(f.w));
    } else {
        float4 f = a.wo[base];
        short h0, l0, h1, l1, h2, l2, h3, l3;
        split_bf16(f.x, h0, l0); split_bf16(f.y, h1, l1);
        split_bf16(f.z, h2, l2); split_bf16(f.w, h3, l3);
        a.woh[base] = make_ushort4(h0, h1, h2, h3);
        a.wol[base] = make_ushort4(l0, l1, l2, l3);
    }
}

// ---------------------------------------------------------------------------
// Fused QKV single-bf16 GEMM. 128x128, BK=64, 768 blocks.
// Q/K blocks: operand-flipped MFMA -> lane holds 4 consecutive hd for one t
//   -> packed ushort4 stores (16 instr vs 64 scalar b16).
// V block: unflipped -> 4 consecutive t per lane -> ushort4 along t (as before).
// ---------------------------------------------------------------------------
__global__ __launch_bounds__(256) void gemm_qkv(
    const short* __restrict__ Xb,
    const short* __restrict__ Bq, const short* __restrict__ Bk,
    const short* __restrict__ Bv,
    short* __restrict__ Qo, short* __restrict__ Ko, short* __restrict__ Vo) {
    __shared__ short sA[128 * 64];
    __shared__ short sB[128 * 64];
    const int K = DMODEL;

    const int tid = threadIdx.x;
    const int lane = tid & 63, wave = tid >> 6;
    const int quad = lane >> 4, col = lane & 15;
    const int m0 = blockIdx.y * 128, n0 = blockIdx.x * 128;
    const int which = n0 >> 10;
    const int nn0 = n0 & 1023;
    const int wm = wave >> 1, wn = wave & 1;

    const short* B = (which == 0) ? Bq : (which == 1) ? Bk : Bv;
    const short* Asrc = Xb + (size_t)m0 * K;
    const short* Bsrc = B + (size_t)nn0 * K;

    const int srow = lane >> 3;
    const int soff = (((lane & 7) ^ srow) * 8);

    floatx4 acc[4][4] = {};

    for (int k0 = 0; k0 < K; k0 += 64) {
        __syncthreads();
#pragma unroll
        for (int j = 0; j < 8; ++j) {
            int idx = wave * 8 + j;
            int sub = idx & 15;
            const short* s = (idx < 16) ? Asrc : Bsrc;
            short* d = (idx < 16) ? sA : sB;
            async16(s + (size_t)(sub * 8 + srow) * K + k0 + soff, d + sub * 512);
        }
        __syncthreads();

#pragma unroll
        for (int s2 = 0; s2 < 2; ++s2) {
            short8 a_b[4], b_b[4];
#pragma unroll
            for (int mi = 0; mi < 4; ++mi) {
                int r = wm * 64 + mi * 16 + col;
                a_b[mi] = *(const short8*)&sA[r * 64 + SWZ8(r, s2 * 4 + quad)];
            }
#pragma unroll
            for (int ni = 0; ni < 4; ++ni) {
                int r = wn * 64 + ni * 16 + col;
                b_b[ni] = *(const short8*)&sB[r * 64 + SWZ8(r, s2 * 4 + quad)];
            }
            if (which == 2) {
#pragma unroll
                for (int mi = 0; mi < 4; ++mi)
#pragma unroll
                    for (int ni = 0; ni < 4; ++ni)
                        acc[mi][ni] = MFMA16(a_b[mi], b_b[ni], acc[mi][ni], 0, 0, 0);
            } else {
                // flipped: C[m = W-row (hd), n = x-row (t)]
#pragma unroll
                for (int mi = 0; mi < 4; ++mi)
#pragma unroll
                    for (int ni = 0; ni < 4; ++ni)
                        acc[mi][ni] = MFMA16(b_b[ni], a_b[mi], acc[mi][ni], 0, 0, 0);
            }
        }
    }

    const int mb = m0 + wm * 64;
    const int nlb = nn0 + wn * 64;
    if (which == 2) {
        // V^T [bh][hd][t], key-chunk swizzle within 64-windows; ushort4 along t
#pragma unroll
        for (int ni = 0; ni < 4; ++ni) {
            int n = nlb + ni * 16 + col;
            int h = n >> 6, hd = n & 63;
#pragma unroll
            for (int mi = 0; mi < 4; ++mi) {
                int m4 = mb + mi * 16 + quad * 4;
                int b = m4 >> 11, t0 = m4 & 2047;
                int chunk = (t0 >> 3) & 7;
                int tsw = (t0 & ~63) | (((chunk ^ (hd & 7)) << 3) | (t0 & 7));
                size_t row = ((size_t)(b * NH + h) * HD + hd) * TSEQ;
                *(ushort4*)&Vo[row + tsw] =
                    make_ushort4(bf16_rne(acc[mi][ni][0]), bf16_rne(acc[mi][ni][1]),
                                 bf16_rne(acc[mi][ni][2]), bf16_rne(acc[mi][ni][3]));
            }
        }
    } else {
        // flipped epilogue: lane holds 4 consecutive hd (quad*4+r) for t = mb+mi*16+col
        short* O = (which == 0) ? Qo : Ko;
        const float sc = (which == 0) ? QSCALE : 1.0f;
#pragma unroll
        for (int mi = 0; mi < 4; ++mi) {
            int m = mb + mi * 16 + col;
            int b = m >> 11, t = m & 2047;
#pragma unroll
            for (int ni = 0; ni < 4; ++ni) {
                int n = nlb + ni * 16 + quad * 4;
                int h = n >> 6, hd = n & 63;
                int hds = (which == 1) ? ((((hd >> 3) ^ (t & 7)) << 3) | (hd & 7)) : hd;
                size_t idx = ((size_t)(b * NH + h) * TSEQ + t) * HD + hds;
                *(ushort4*)&O[idx] =
                    make_ushort4(bf16_rne(acc[mi][ni][0] * sc), bf16_rne(acc[mi][ni][1] * sc),
                                 bf16_rne(acc[mi][ni][2] * sc), bf16_rne(acc[mi][ni][3] * sc));
            }
        }
    }
}

// ---------------------------------------------------------------------------
// Flash attention, fully transposed-lane form, 512 thr = 8 waves, 16 q/wave.
// S^T = MFMA(K, Q): lane -> 4 consecutive keys for q=col  -> b64 sP writes.
// O^T = MFMA(V, P): lane -> 4 consecutive hd  for q=col  -> b64 ctx stores.
// l is per-lane (q=col), reduced over quads once at the end.
// sP: per-wave [q][key] 16x64, chunk-XOR swizzled by (q&7).
// ---------------------------------------------------------------------------
__global__ __launch_bounds__(512) void attn_bf16(
    const short* __restrict__ Qb, const short* __restrict__ Kb,
    const short* __restrict__ Vb, short* __restrict__ Cb) {
    __shared__ short sK[2][64 * 64];
    __shared__ short sV[2][64 * 64];
    __shared__ short sP[8][16 * 64];

    const int tid = threadIdx.x;
    const int lane = tid & 63, wave = tid >> 6;
    const int quad = lane >> 4, col = lane & 15;
    const int qt = blockIdx.x, bh = blockIdx.y;
    const size_t bhoff = (size_t)bh * TSEQ * HD;

    // Q as B-operand frags: B[n=q=col][k=quad*8+j] — same indexing as A-frag
    const size_t qrow = (size_t)(qt * 128 + wave * 16 + col) * HD;
    short8 qf[2];
#pragma unroll
    for (int c = 0; c < 2; ++c)
        qf[c] = *(const short8*)&Qb[bhoff + qrow + c * 32 + quad * 8];

    const int srow = lane >> 3;
    const int schunk = (lane & 7) * 8;   // K/V globally pre-swizzled
    short* sPw = sP[wave];

    float l_r = 0.f;        // per-lane: q = col
    floatx4 O[4] = {};      // O[hd-tile][reg]: hd = ni*16 + quad*4 + r, q = col

    for (int kt = 0; kt < 16; ++kt) {
        __syncthreads();
#pragma unroll
        for (int j = 0; j < 4; ++j) {
            int n = wave * 4 + j;          // 0..31
            int isv = n >> 4;
            int tile = (n >> 3) & 1;
            int sub = n & 7;
            if (!isv) {
                async16(Kb + bhoff + (size_t)(kt * 128 + tile * 64 + sub * 8 + srow) * HD + schunk,
                        &sK[tile][sub * 512]);
            } else {
                async16(Vb + bhoff + (size_t)(sub * 8 + srow) * TSEQ + kt * 128 + tile * 64 + schunk,
                        &sV[tile][sub * 512]);
            }
        }
        __syncthreads();

#pragma unroll
        for (int u = 0; u < 2; ++u) {
            // S^T[key][q]: A = K (m=key), B = Q (n=q=col)
            floatx4 s[4] = {};
#pragma unroll
            for (int k4 = 0; k4 < 4; ++k4) {
                int r = k4 * 16 + col;   // key row in sK (A-frag: m = col-indexed)
#pragma unroll
                for (int c = 0; c < 2; ++c) {
                    int ch = (((c * 4 + quad) ^ (r & 7)) << 3);
                    short8 kf = *(const short8*)&sK[u][r * 64 + ch];
                    s[k4] = MFMA16(kf, qf[c], s[k4], 0, 0, 0);
                }
            }

            // p = 2^s; per-lane l; packed b64 write of 4 consecutive keys
#pragma unroll
            for (int k4 = 0; k4 < 4; ++k4) {
                float p0 = __builtin_amdgcn_exp2f(s[k4][0]);
                float p1 = __builtin_amdgcn_exp2f(s[k4][1]);
                float p2 = __builtin_amdgcn_exp2f(s[k4][2]);
                float p3 = __builtin_amdgcn_exp2f(s[k4][3]);
                l_r += (p0 + p1) + (p2 + p3);
                uint2 pk;
                pk.x = pack_bf16x2(p0, p1);
                pk.y = pack_bf16x2(p2, p3);
                // key base = k4*16 + quad*4; chunk = k4*2 + (quad>>1)
                int swz = (k4 * 2 + (quad >> 1)) ^ (col & 7);
                *(uint2*)&sPw[col * 64 + swz * 8 + (quad & 1) * 4] = pk;
            }

            // O^T[hd][q]: A = V^T (m=hd), B = P (n=q=col, k=key)
#pragma unroll
            for (int c = 0; c < 2; ++c) {
                int pswz = ((c * 4 + quad) ^ (col & 7)) * 8;
                short8 pf = *(const short8*)&sPw[col * 64 + pswz];
#pragma unroll
                for (int ni = 0; ni < 4; ++ni) {
                    int r = ni * 16 + col;   // hd row in sV
                    int ch = (((c * 4 + quad) ^ (r & 7)) << 3);
                    short8 vf = *(const short8*)&sV[u][r * 64 + ch];
                    O[ni] = MFMA16(vf, pf, O[ni], 0, 0, 0);
                }
            }
        }
    }

    // l: reduce over quad partners (lanes col, col+16, col+32, col+48)
    float t = l_r;
    t += __shfl_xor(t, 16);
    t += __shfl_xor(t, 32);
    const float inv = 1.0f / t;

    const int b = bh >> 4, h = bh & 15;
    const int trow = qt * 128 + wave * 16 + col;
    const size_t obase = (size_t)(b * TSEQ + trow) * DMODEL + h * 64;
#pragma unroll
    for (int ni = 0; ni < 4; ++ni) {
        uint2 pk;
        pk.x = pack_bf16x2(O[ni][0] * inv, O[ni][1] * inv);
        pk.y = pack_bf16x2(O[ni][2] * inv, O[ni][3] * inv);
        *(uint2*)&Cb[obase + ni * 16 + quad * 4] = pk;
    }
}

// ---------------------------------------------------------------------------
// Out-proj 2-term, operand-flipped: C[m = Wo-row (n_out), n = ctx-row (m_out)]
// -> lane holds 4 consecutive n_out for one m_out -> coalesced dwordx4 stores.
// 128x64 tile, BK=64, 512 blocks.
// ---------------------------------------------------------------------------
__global__ __launch_bounds__(256) void gemm_out(
    const short* __restrict__ Ab,
    const short* __restrict__ Bh, const short* __restrict__ Bl,
    const float* __restrict__ bias, float* __restrict__ Of) {
    __shared__ short sA[128 * 64];
    __shared__ short sBh[64 * 64];
    __shared__ short sBl[64 * 64];
    const int K = DMODEL, N = DMODEL;

    const int tid = threadIdx.x;
    const int lane = tid & 63, wave = tid >> 6;
    const int quad = lane >> 4, col = lane & 15;
    const int m0 = blockIdx.y * 128, n0 = blockIdx.x * 64;
    const int wm = wave >> 1, wn = wave & 1;

    const short* Asrc = Ab + (size_t)m0 * K;
    const short* Bhsrc = Bh + (size_t)n0 * K;
    const short* Blsrc = Bl + (size_t)n0 * K;
    const int srow = lane >> 3;
    const int soff = (((lane & 7) ^ srow) * 8);

    floatx4 acc[4][2] = {};

    for (int k0 = 0; k0 < K; k0 += 64) {
        __syncthreads();
#pragma unroll
        for (int j = 0; j < 8; ++j) {
            int idx = wave * 8 + j;
            int buf = (idx < 16) ? 0 : (idx < 24) ? 1 : 2;
            int sub = (buf == 0) ? idx : (buf == 1) ? idx - 16 : idx - 24;
            const short* s = (buf == 0) ? Asrc : (buf == 1) ? Bhsrc : Blsrc;
            short* d = (buf == 0) ? sA : (buf == 1) ? sBh : sBl;
            async16(s + (size_t)(sub * 8 + srow) * K + k0 + soff, d + sub * 512);
        }
        __syncthreads();

#pragma unroll
        for (int s2 = 0; s2 < 2; ++s2) {
            short8 a_b[4], b_h[2], b_l[2];
#pragma unroll
            for (int mi = 0; mi < 4; ++mi) {
                int r = wm * 64 + mi * 16 + col;
                a_b[mi] = *(const short8*)&sA[r * 64 + SWZ8(r, s2 * 4 + quad)];
            }
#pragma unroll
            for (int ni = 0; ni < 2; ++ni) {
                int r = wn * 32 + ni * 16 + col;
                b_h[ni] = *(const short8*)&sBh[r * 64 + SWZ8(r, s2 * 4 + quad)];
                b_l[ni] = *(const short8*)&sBl[r * 64 + SWZ8(r, s2 * 4 + quad)];
            }
#pragma unroll
            for (int mi = 0; mi < 4; ++mi)
#pragma unroll
                for (int ni = 0; ni < 2; ++ni) {
                    acc[mi][ni] = MFMA16(b_h[ni], a_b[mi], acc[mi][ni], 0, 0, 0);
                    acc[mi][ni] = MFMA16(b_l[ni], a_b[mi], acc[mi][ni], 0, 0, 0);
                }
        }
    }

    // flipped epilogue: m_out = mb + mi*16 + col; n_out = nb + ni*16 + quad*4 + r
    const int mb = m0 + wm * 64, nb = n0 + wn * 32;
#pragma unroll
    for (int mi = 0; mi < 4; ++mi) {
        int m = mb + mi * 16 + col;
#pragma unroll
        for (int ni = 0; ni < 2; ++ni) {
            int n = nb + ni * 16 + quad * 4;
            float4 bv = *(const float4*)&bias[n];
            float4 o = make_float4(acc[mi][ni][0] + bv.x, acc[mi][ni][1] + bv.y,
                                   acc[mi][ni][2] + bv.z, acc[mi][ni][3] + bv.w);
            *(float4*)&Of[(size_t)m * N + n] = o;
        }
    }
}

// ---------------------------------------------------------------------------
extern "C" void kernel_launch(void* const* d_in, const int* in_sizes, int n_in,
                              void* d_out, int out_size, void* d_ws, size_t ws_size,
                              hipStream_t stream) {
    const float* x  = (const float*)d_in[0];
    const float* Wq = (const float*)d_in[1];
    const float* Wk = (const float*)d_in[2];
    const float* Wv = (const float*)d_in[3];
    const float* Wo = (const float*)d_in[4];
    const float* bo = (const float*)d_in[5];
    float* out = (float*)d_out;

    const size_t NX = (size_t)BROWS * DMODEL;   // 4M
    const size_t NW = (size_t)DMODEL * DMODEL;  // 1M
    short* p = (short*)d_ws;
    short *xb = p;
    short *wqb = xb + NX;
    short *wkb = wqb + NW;
    short *wvb = wkb + NW;
    short *woh = wvb + NW; short *wol = woh + NW;
    short *qb = wol + NW;
    short *kb = qb + NX;
    short *vb = kb + NX;
    short *cb = vb + NX;

    PackArgs pa;
    pa.x = (const float4*)x; pa.xb = (ushort4*)xb;
    pa.w[0] = (const float4*)Wq; pa.wb[0] = (ushort4*)wqb;
    pa.w[1] = (const float4*)Wk; pa.wb[1] = (ushort4*)wkb;
    pa.w[2] = (const float4*)Wv; pa.wb[2] = (ushort4*)wvb;
    pa.wo = (const float4*)Wo; pa.woh = (ushort4*)woh; pa.wol = (ushort4*)wol;
    pack_all<<<dim3(1024, 5), dim3(256), 0, stream>>>(pa);

    gemm_qkv<<<dim3(3 * DMODEL / 128, BROWS / 128), dim3(256), 0, stream>>>(
        xb, wqb, wkb, wvb, qb, kb, vb);

    attn_bf16<<<dim3(TSEQ / 128, BH), dim3(512), 0, stream>>>(qb, kb, vb, cb);

    gemm_out<<<dim3(DMODEL / 64, BROWS / 128), dim3(256), 0, stream>>>(cb, woh, wol, bo, out);
}

// Round 9
// 199.207 us; speedup vs baseline: 1.1806x; 1.0019x over previous
//
#include <hip/hip_runtime.h>
#include <hip/hip_bf16.h>
#include <math.h>
#include <stdint.h>
#include <string.h>

#define TSEQ 2048
#define DMODEL 1024
#define NH 16
#define HD 64
#define BROWS 4096   // b*t
#define BH 32        // b*h

typedef __attribute__((ext_vector_type(8))) short short8;
typedef __attribute__((ext_vector_type(4))) float floatx4;

#define MFMA16 __builtin_amdgcn_mfma_f32_16x16x32_bf16
// 3-bit chunk-XOR swizzle on 64-short (128 B) rows
#define SWZ8(r, q) ((((q) ^ ((r) & 7)) * 8))

#define QSCALE 0.18033688011112042f   // 0.125 * log2(e); p = exp2(s) = exp(s/log2e)

__device__ __forceinline__ unsigned short bf16_rne(float f) {
    uint32_t u = __float_as_uint(f);
    u += 0x7FFFu + ((u >> 16) & 1u);
    return (unsigned short)(u >> 16);
}

__device__ __forceinline__ uint32_t pack_bf16x2(float a, float b) {
    __hip_bfloat162 h = __float22bfloat162_rn(float2{a, b});
    uint32_t r;
    memcpy(&r, &h, 4);
    return r;
}

__device__ __forceinline__ void split_bf16(float f, short& hi, short& lo) {
    uint32_t u = __float_as_uint(f);
    hi = (short)(u >> 16);
    float hif = __uint_as_float(u & 0xFFFF0000u);
    lo = (short)bf16_rne(f - hif);
}

__device__ __forceinline__ void async16(const void* g, void* l) {
    __builtin_amdgcn_global_load_lds(
        (__attribute__((address_space(1))) const uint32_t*)g,
        (__attribute__((address_space(3))) uint32_t*)l, 16, 0, 0);
}

// ---------------------------------------------------------------------------
// Fused pack (unchanged)
// ---------------------------------------------------------------------------
struct PackArgs {
    const float4* x;
    ushort4* xb;
    const float4* w[3];   // Wq, Wk, Wv
    ushort4* wb[3];
    const float4* wo;
    ushort4* woh;
    ushort4* wol;
};
__global__ __launch_bounds__(256) void pack_all(PackArgs a) {
    const int y = blockIdx.y;
    const int base = blockIdx.x * 256 + threadIdx.x;
    if (y == 0) {
#pragma unroll
        for (int it = 0; it < 4; ++it) {
            int i = base + it * 262144;
            float4 f = a.x[i];
            a.xb[i] = make_ushort4(bf16_rne(f.x), bf16_rne(f.y),
                                   bf16_rne(f.z), bf16_rne(f.w));
        }
    } else if (y <= 3) {
        int w = y - 1;
        float4 f = a.w[w][base];
        a.wb[w][base] = make_ushort4(bf16_rne(f.x), bf16_rne(f.y),
                                     bf16_rne(f.z), bf16_rne(f.w));
    } else {
        float4 f = a.wo[base];
        short h0, l0, h1, l1, h2, l2, h3, l3;
        split_bf16(f.x, h0, l0); split_bf16(f.y, h1, l1);
        split_bf16(f.z, h2, l2); split_bf16(f.w, h3, l3);
        a.woh[base] = make_ushort4(h0, h1, h2, h3);
        a.wol[base] = make_ushort4(l0, l1, l2, l3);
    }
}

// ---------------------------------------------------------------------------
// Fused QKV single-bf16 GEMM. 128x128, BK=64, 768 blocks.
// Q/K: operand-flipped -> packed ushort4 stores.
// V: [bh][hd][t], within-64-window key positions permuted by kappa^-1
//    (s = {t5, t3t2, t4, t1t0}) so attn's PV B-operand comes straight from
//    registers; then chunk-XOR by hd&7 as before.
// ---------------------------------------------------------------------------
__global__ __launch_bounds__(256) void gemm_qkv(
    const short* __restrict__ Xb,
    const short* __restrict__ Bq, const short* __restrict__ Bk,
    const short* __restrict__ Bv,
    short* __restrict__ Qo, short* __restrict__ Ko, short* __restrict__ Vo) {
    __shared__ short sA[128 * 64];
    __shared__ short sB[128 * 64];
    const int K = DMODEL;

    const int tid = threadIdx.x;
    const int lane = tid & 63, wave = tid >> 6;
    const int quad = lane >> 4, col = lane & 15;
    const int m0 = blockIdx.y * 128, n0 = blockIdx.x * 128;
    const int which = n0 >> 10;
    const int nn0 = n0 & 1023;
    const int wm = wave >> 1, wn = wave & 1;

    const short* B = (which == 0) ? Bq : (which == 1) ? Bk : Bv;
    const short* Asrc = Xb + (size_t)m0 * K;
    const short* Bsrc = B + (size_t)nn0 * K;

    const int srow = lane >> 3;
    const int soff = (((lane & 7) ^ srow) * 8);

    floatx4 acc[4][4] = {};

    for (int k0 = 0; k0 < K; k0 += 64) {
        __syncthreads();
#pragma unroll
        for (int j = 0; j < 8; ++j) {
            int idx = wave * 8 + j;
            int sub = idx & 15;
            const short* s = (idx < 16) ? Asrc : Bsrc;
            short* d = (idx < 16) ? sA : sB;
            async16(s + (size_t)(sub * 8 + srow) * K + k0 + soff, d + sub * 512);
        }
        __syncthreads();

#pragma unroll
        for (int s2 = 0; s2 < 2; ++s2) {
            short8 a_b[4], b_b[4];
#pragma unroll
            for (int mi = 0; mi < 4; ++mi) {
                int r = wm * 64 + mi * 16 + col;
                a_b[mi] = *(const short8*)&sA[r * 64 + SWZ8(r, s2 * 4 + quad)];
            }
#pragma unroll
            for (int ni = 0; ni < 4; ++ni) {
                int r = wn * 64 + ni * 16 + col;
                b_b[ni] = *(const short8*)&sB[r * 64 + SWZ8(r, s2 * 4 + quad)];
            }
            if (which == 2) {
#pragma unroll
                for (int mi = 0; mi < 4; ++mi)
#pragma unroll
                    for (int ni = 0; ni < 4; ++ni)
                        acc[mi][ni] = MFMA16(a_b[mi], b_b[ni], acc[mi][ni], 0, 0, 0);
            } else {
#pragma unroll
                for (int mi = 0; mi < 4; ++mi)
#pragma unroll
                    for (int ni = 0; ni < 4; ++ni)
                        acc[mi][ni] = MFMA16(b_b[ni], a_b[mi], acc[mi][ni], 0, 0, 0);
            }
        }
    }

    const int mb = m0 + wm * 64;
    const int nlb = nn0 + wn * 64;
    if (which == 2) {
        // V^T [bh][hd][t], kappa-permuted window position + chunk-XOR swizzle
#pragma unroll
        for (int ni = 0; ni < 4; ++ni) {
            int n = nlb + ni * 16 + col;
            int h = n >> 6, hd = n & 63;
#pragma unroll
            for (int mi = 0; mi < 4; ++mi) {
                int m4 = mb + mi * 16 + quad * 4;
                int b = m4 >> 11, t0 = m4 & 2047;
                // kappa^-1: key bits [t5][t4][t3t2][t1t0] -> s = [t5][t3t2][t4][t1t0]
                int sw = (t0 & 32) | ((t0 & 12) << 1) | ((t0 & 16) >> 2);
                int tsw = (t0 & ~63) | ((((sw >> 3) ^ (hd & 7)) << 3) | (sw & 7));
                size_t row = ((size_t)(b * NH + h) * HD + hd) * TSEQ;
                *(ushort4*)&Vo[row + tsw] =
                    make_ushort4(bf16_rne(acc[mi][ni][0]), bf16_rne(acc[mi][ni][1]),
                                 bf16_rne(acc[mi][ni][2]), bf16_rne(acc[mi][ni][3]));
            }
        }
    } else {
        short* O = (which == 0) ? Qo : Ko;
        const float sc = (which == 0) ? QSCALE : 1.0f;
#pragma unroll
        for (int mi = 0; mi < 4; ++mi) {
            int m = mb + mi * 16 + col;
            int b = m >> 11, t = m & 2047;
#pragma unroll
            for (int ni = 0; ni < 4; ++ni) {
                int n = nlb + ni * 16 + quad * 4;
                int h = n >> 6, hd = n & 63;
                int hds = (which == 1) ? ((((hd >> 3) ^ (t & 7)) << 3) | (hd & 7)) : hd;
                size_t idx = ((size_t)(b * NH + h) * TSEQ + t) * HD + hds;
                *(ushort4*)&O[idx] =
                    make_ushort4(bf16_rne(acc[mi][ni][0] * sc), bf16_rne(acc[mi][ni][1] * sc),
                                 bf16_rne(acc[mi][ni][2] * sc), bf16_rne(acc[mi][ni][3] * sc));
            }
        }
    }
}

// ---------------------------------------------------------------------------
// Flash attention, no-sP form. 512 thr = 8 waves, 16 q/wave, 128 keys/round.
// S^T = MFMA(K, Q): lane holds keys {16*k4 + 4*quad + r} for q = col.
// V columns stored in kappa order -> PV B-operand built directly from the
// exp2'd S registers: pf[c] = [p[2c][0..3], p[2c+1][0..3]]. Zero P LDS traffic.
// ---------------------------------------------------------------------------
__global__ __launch_bounds__(512) void attn_bf16(
    const short* __restrict__ Qb, const short* __restrict__ Kb,
    const short* __restrict__ Vb, short* __restrict__ Cb) {
    __shared__ short sK[2][64 * 64];
    __shared__ short sV[2][64 * 64];

    const int tid = threadIdx.x;
    const int lane = tid & 63, wave = tid >> 6;
    const int quad = lane >> 4, col = lane & 15;
    const int qt = blockIdx.x, bh = blockIdx.y;
    const size_t bhoff = (size_t)bh * TSEQ * HD;

    // Q as B-operand frags: B[n=q=col][k=quad*8+j]
    const size_t qrow = (size_t)(qt * 128 + wave * 16 + col) * HD;
    short8 qf[2];
#pragma unroll
    for (int c = 0; c < 2; ++c)
        qf[c] = *(const short8*)&Qb[bhoff + qrow + c * 32 + quad * 8];

    const int srow = lane >> 3;
    const int schunk = (lane & 7) * 8;   // K/V globally pre-swizzled

    float l_r = 0.f;        // per-lane: q = col
    floatx4 O[4] = {};      // O^T: hd = ni*16 + quad*4 + r, q = col

    for (int kt = 0; kt < 16; ++kt) {
        __syncthreads();
#pragma unroll
        for (int j = 0; j < 4; ++j) {
            int n = wave * 4 + j;          // 0..31
            int isv = n >> 4;
            int tile = (n >> 3) & 1;
            int sub = n & 7;
            if (!isv) {
                async16(Kb + bhoff + (size_t)(kt * 128 + tile * 64 + sub * 8 + srow) * HD + schunk,
                        &sK[tile][sub * 512]);
            } else {
                async16(Vb + bhoff + (size_t)(sub * 8 + srow) * TSEQ + kt * 128 + tile * 64 + schunk,
                        &sV[tile][sub * 512]);
            }
        }
        __syncthreads();

#pragma unroll
        for (int u = 0; u < 2; ++u) {
            // S^T[key][q]: A = K (m=key), B = Q (n=q=col)
            floatx4 s[4] = {};
#pragma unroll
            for (int k4 = 0; k4 < 4; ++k4) {
                int r = k4 * 16 + col;
#pragma unroll
                for (int c = 0; c < 2; ++c) {
                    int ch = (((c * 4 + quad) ^ (r & 7)) << 3);
                    short8 kf = *(const short8*)&sK[u][r * 64 + ch];
                    s[k4] = MFMA16(kf, qf[c], s[k4], 0, 0, 0);
                }
            }

            // p = 2^s in registers; per-lane l
            float p[4][4];
#pragma unroll
            for (int k4 = 0; k4 < 4; ++k4)
#pragma unroll
                for (int r4 = 0; r4 < 4; ++r4) {
                    p[k4][r4] = __builtin_amdgcn_exp2f(s[k4][r4]);
                    l_r += p[k4][r4];
                }

            // O^T += MFMA(V^T, P): pf built directly from registers (kappa order)
#pragma unroll
            for (int c = 0; c < 2; ++c) {
                union { short8 v; uint32_t w[4]; } pf;
                pf.w[0] = pack_bf16x2(p[2 * c][0], p[2 * c][1]);
                pf.w[1] = pack_bf16x2(p[2 * c][2], p[2 * c][3]);
                pf.w[2] = pack_bf16x2(p[2 * c + 1][0], p[2 * c + 1][1]);
                pf.w[3] = pack_bf16x2(p[2 * c + 1][2], p[2 * c + 1][3]);
#pragma unroll
                for (int ni = 0; ni < 4; ++ni) {
                    int r = ni * 16 + col;   // hd row in sV
                    int ch = (((c * 4 + quad) ^ (r & 7)) << 3);
                    short8 vf = *(const short8*)&sV[u][r * 64 + ch];
                    O[ni] = MFMA16(vf, pf.v, O[ni], 0, 0, 0);
                }
            }
        }
    }

    // l: reduce over quad partners (lanes col, col+16, col+32, col+48)
    float t = l_r;
    t += __shfl_xor(t, 16);
    t += __shfl_xor(t, 32);
    const float inv = 1.0f / t;

    const int b = bh >> 4, h = bh & 15;
    const int trow = qt * 128 + wave * 16 + col;
    const size_t obase = (size_t)(b * TSEQ + trow) * DMODEL + h * 64;
#pragma unroll
    for (int ni = 0; ni < 4; ++ni) {
        uint2 pk;
        pk.x = pack_bf16x2(O[ni][0] * inv, O[ni][1] * inv);
        pk.y = pack_bf16x2(O[ni][2] * inv, O[ni][3] * inv);
        *(uint2*)&Cb[obase + ni * 16 + quad * 4] = pk;
    }
}

// ---------------------------------------------------------------------------
// Out-proj 2-term, operand-flipped (unchanged from R8). 128x64, BK=64.
// ---------------------------------------------------------------------------
__global__ __launch_bounds__(256) void gemm_out(
    const short* __restrict__ Ab,
    const short* __restrict__ Bh, const short* __restrict__ Bl,
    const float* __restrict__ bias, float* __restrict__ Of) {
    __shared__ short sA[128 * 64];
    __shared__ short sBh[64 * 64];
    __shared__ short sBl[64 * 64];
    const int K = DMODEL, N = DMODEL;

    const int tid = threadIdx.x;
    const int lane = tid & 63, wave = tid >> 6;
    const int quad = lane >> 4, col = lane & 15;
    const int m0 = blockIdx.y * 128, n0 = blockIdx.x * 64;
    const int wm = wave >> 1, wn = wave & 1;

    const short* Asrc = Ab + (size_t)m0 * K;
    const short* Bhsrc = Bh + (size_t)n0 * K;
    const short* Blsrc = Bl + (size_t)n0 * K;
    const int srow = lane >> 3;
    const int soff = (((lane & 7) ^ srow) * 8);

    floatx4 acc[4][2] = {};

    for (int k0 = 0; k0 < K; k0 += 64) {
        __syncthreads();
#pragma unroll
        for (int j = 0; j < 8; ++j) {
            int idx = wave * 8 + j;
            int buf = (idx < 16) ? 0 : (idx < 24) ? 1 : 2;
            int sub = (buf == 0) ? idx : (buf == 1) ? idx - 16 : idx - 24;
            const short* s = (buf == 0) ? Asrc : (buf == 1) ? Bhsrc : Blsrc;
            short* d = (buf == 0) ? sA : (buf == 1) ? sBh : sBl;
            async16(s + (size_t)(sub * 8 + srow) * K + k0 + soff, d + sub * 512);
        }
        __syncthreads();

#pragma unroll
        for (int s2 = 0; s2 < 2; ++s2) {
            short8 a_b[4], b_h[2], b_l[2];
#pragma unroll
            for (int mi = 0; mi < 4; ++mi) {
                int r = wm * 64 + mi * 16 + col;
                a_b[mi] = *(const short8*)&sA[r * 64 + SWZ8(r, s2 * 4 + quad)];
            }
#pragma unroll
            for (int ni = 0; ni < 2; ++ni) {
                int r = wn * 32 + ni * 16 + col;
                b_h[ni] = *(const short8*)&sBh[r * 64 + SWZ8(r, s2 * 4 + quad)];
                b_l[ni] = *(const short8*)&sBl[r * 64 + SWZ8(r, s2 * 4 + quad)];
            }
#pragma unroll
            for (int mi = 0; mi < 4; ++mi)
#pragma unroll
                for (int ni = 0; ni < 2; ++ni) {
                    acc[mi][ni] = MFMA16(b_h[ni], a_b[mi], acc[mi][ni], 0, 0, 0);
                    acc[mi][ni] = MFMA16(b_l[ni], a_b[mi], acc[mi][ni], 0, 0, 0);
                }
        }
    }

    const int mb = m0 + wm * 64, nb = n0 + wn * 32;
#pragma unroll
    for (int mi = 0; mi < 4; ++mi) {
        int m = mb + mi * 16 + col;
#pragma unroll
        for (int ni = 0; ni < 2; ++ni) {
            int n = nb + ni * 16 + quad * 4;
            float4 bv = *(const float4*)&bias[n];
            float4 o = make_float4(acc[mi][ni][0] + bv.x, acc[mi][ni][1] + bv.y,
                                   acc[mi][ni][2] + bv.z, acc[mi][ni][3] + bv.w);
            *(float4*)&Of[(size_t)m * N + n] = o;
        }
    }
}

// ---------------------------------------------------------------------------
extern "C" void kernel_launch(void* const* d_in, const int* in_sizes, int n_in,
                              void* d_out, int out_size, void* d_ws, size_t ws_size,
                              hipStream_t stream) {
    const float* x  = (const float*)d_in[0];
    const float* Wq = (const float*)d_in[1];
    const float* Wk = (const float*)d_in[2];
    const float* Wv = (const float*)d_in[3];
    const float* Wo = (const float*)d_in[4];
    const float* bo = (const float*)d_in[5];
    float* out = (float*)d_out;

    const size_t NX = (size_t)BROWS * DMODEL;   // 4M
    const size_t NW = (size_t)DMODEL * DMODEL;  // 1M
    short* p = (short*)d_ws;
    short *xb = p;
    short *wqb = xb + NX;
    short *wkb = wqb + NW;
    short *wvb = wkb + NW;
    short *woh = wvb + NW; short *wol = woh + NW;
    short *qb = wol + NW;
    short *kb = qb + NX;
    short *vb = kb + NX;
    short *cb = vb + NX;

    PackArgs pa;
    pa.x = (const float4*)x; pa.xb = (ushort4*)xb;
    pa.w[0] = (const float4*)Wq; pa.wb[0] = (ushort4*)wqb;
    pa.w[1] = (const float4*)Wk; pa.wb[1] = (ushort4*)wkb;
    pa.w[2] = (const float4*)Wv; pa.wb[2] = (ushort4*)wvb;
    pa.wo = (const float4*)Wo; pa.woh = (ushort4*)woh; pa.wol = (ushort4*)wol;
    pack_all<<<dim3(1024, 5), dim3(256), 0, stream>>>(pa);

    gemm_qkv<<<dim3(3 * DMODEL / 128, BROWS / 128), dim3(256), 0, stream>>>(
        xb, wqb, wkb, wvb, qb, kb, vb);

    attn_bf16<<<dim3(TSEQ / 128, BH), dim3(512), 0, stream>>>(qb, kb, vb, cb);

    gemm_out<<<dim3(DMODEL / 64, BROWS / 128), dim3(256), 0, stream>>>(cb, woh, wol, bo, out);
}